// Round 8
// baseline (376.599 us; speedup 1.0000x reference)
//
#include <hip/hip_runtime.h>
#include <math.h>

#define NEG_SLOPE 0.01f
#define ELLW 40   // max in-degree per relation (Poisson(10); P(overflow)~1e-8, clamped)
#define NSH 4     // out-degree shard count (per-line RMW conflict reduction)

typedef float f4 __attribute__((ext_vector_type(4)));
typedef __bf16 bf16x8 __attribute__((ext_vector_type(8)));
typedef __bf16 bf16x4 __attribute__((ext_vector_type(4)));
typedef _Float16 h4 __attribute__((ext_vector_type(4)));
typedef _Float16 h8 __attribute__((ext_vector_type(8)));

// ---------------- W prep (transpose + bf16 split, 5 weights) + sharded out-degree count ----------------
// degree region is zeroed by hipMemsetAsync before this kernel.
// blocks [0,320): W prep ; blocks [320,320+CB): grid-strided out-degree atomics into shard (b & 3).
__global__ __launch_bounds__(256) void prep_w_count(
    const float* __restrict__ W0, const float* __restrict__ W1,
    const float* __restrict__ W2, const float* __restrict__ W3,
    const float* __restrict__ W4, __bf16* __restrict__ H, __bf16* __restrict__ L,
    const int* __restrict__ s0, int* sd0, int E0, int L0,
    const int* __restrict__ s1, int* sd1, int E1, int L1,
    const int* __restrict__ s2, int* sd2, int E2, int L2, int CB)
{
    const int b = blockIdx.x;
    if (b < 320) {
        const int y = b >> 6;
        const float* W = y == 0 ? W0 : y == 1 ? W1 : y == 2 ? W2 : y == 3 ? W3 : W4;
        int idx = (b & 63) * 256 + threadIdx.x;   // 0..16383
        int k = idx >> 7, n = idx & 127;
        float w = W[idx];
        __bf16 h = (__bf16)w;
        __bf16 l = (__bf16)(w - (float)h);
        H[(size_t)y * 16384 + n * 128 + k] = h;
        L[(size_t)y * 16384 + n * 128 + k] = l;
    } else {
        int cb = b - 320;
        int sh = cb & (NSH - 1);
        int stride = CB * 256;
        int Etot = E0 + E1 + E2;
        int* p0 = sd0 + sh * L0;
        int* p1 = sd1 + sh * L1;
        int* p2 = sd2 + sh * L2;
        for (int i = cb * 256 + (int)threadIdx.x; i < Etot; i += stride) {
            int s; int* sd;
            if (i < E0)           { s = s0[i]; sd = p0; }
            else if (i < E0 + E1) { s = s1[i - E0]; sd = p1; }
            else                  { s = s2[i - E0 - E1]; sd = p2; }
            atomicAdd(&sd[s], 1);
        }
    }
}

// ---------------- MFMA from pre-staged LDS A-tile: C[64,128] = A_lds @ W (+src-norm epilogue) ----------------
// SCALE: rdeg is NSH-sharded with stride M; epilogue sums shards then rsqrt.
template <int SCALE>
__device__ __forceinline__ void mfma_from_lds(
    const __bf16* __restrict__ Bh, const __bf16* __restrict__ Bl,
    _Float16* __restrict__ C, const int* __restrict__ rdeg, int M, int row0, int tid,
    __bf16 (*Ah)[136], __bf16 (*Al)[136])
{
    const int lane = tid & 63;
    const int wid = tid >> 6;
    const int lm = lane & 15;
    const int lq = lane >> 4;
    const int mbase = (wid & 1) * 32;
    const int nbase = (wid >> 1) * 64;

    f4 acc[2][4] = {};
#pragma unroll
    for (int kc = 0; kc < 4; ++kc) {
        const int koff = kc * 32 + lq * 8;
        bf16x8 ah[2], al[2], bh[4], bl[4];
#pragma unroll
        for (int mi = 0; mi < 2; ++mi) {
            ah[mi] = *(const bf16x8*)&Ah[mbase + mi * 16 + lm][koff];
            al[mi] = *(const bf16x8*)&Al[mbase + mi * 16 + lm][koff];
        }
#pragma unroll
        for (int ni = 0; ni < 4; ++ni) {
            size_t boff = (size_t)(nbase + ni * 16 + lm) * 128 + koff;
            bh[ni] = *(const bf16x8*)(Bh + boff);
            bl[ni] = *(const bf16x8*)(Bl + boff);
        }
#pragma unroll
        for (int mi = 0; mi < 2; ++mi)
#pragma unroll
            for (int ni = 0; ni < 4; ++ni) {
                acc[mi][ni] = __builtin_amdgcn_mfma_f32_16x16x32_bf16(ah[mi], bh[ni], acc[mi][ni], 0, 0, 0);
                acc[mi][ni] = __builtin_amdgcn_mfma_f32_16x16x32_bf16(al[mi], bh[ni], acc[mi][ni], 0, 0, 0);
                acc[mi][ni] = __builtin_amdgcn_mfma_f32_16x16x32_bf16(ah[mi], bl[ni], acc[mi][ni], 0, 0, 0);
            }
    }

#pragma unroll
    for (int mi = 0; mi < 2; ++mi) {
        int rbase = row0 + mbase + mi * 16 + lq * 4;
#pragma unroll
        for (int r = 0; r < 4; ++r) {
            int row = rbase + r;
            if (row < M) {
                float s = 1.0f;
                if (SCALE) {
                    int d = rdeg[row] + rdeg[row + M] + rdeg[row + 2 * M] + rdeg[row + 3 * M];
                    s = rsqrtf(fmaxf((float)d, 1.0f));
                }
#pragma unroll
                for (int ni = 0; ni < 4; ++ni)
                    C[(size_t)row * 128 + nbase + ni * 16 + lm] = (_Float16)(acc[mi][ni][r] * s);
            }
        }
    }
}

// ---------------- GEMM core: stage f32 A from global (optional relu) + MFMA ----------------
template <int RELU, int SCALE>
__device__ __forceinline__ void gemm_core(const float* __restrict__ A,
    const __bf16* __restrict__ Bh, const __bf16* __restrict__ Bl,
    _Float16* __restrict__ C, const int* __restrict__ rdeg, int M, int row0, int tid,
    __bf16 (*Ah)[136], __bf16 (*Al)[136])
{
#pragma unroll
    for (int it = 0; it < 8; ++it) {
        int idx4 = it * 256 + tid;
        int r = idx4 >> 5;
        int c = (idx4 & 31) << 2;
        int rg = row0 + r;
        f4 v = {0.f, 0.f, 0.f, 0.f};
        if (rg < M) v = *(const f4*)(A + (size_t)rg * 128 + c);
        if (RELU) {
#pragma unroll
            for (int j = 0; j < 4; ++j) v[j] = v[j] >= 0.f ? v[j] : v[j] * NEG_SLOPE;
        }
        bf16x4 hv, lv;
#pragma unroll
        for (int j = 0; j < 4; ++j) {
            __bf16 h = (__bf16)v[j];
            hv[j] = h;
            lv[j] = (__bf16)(v[j] - (float)h);
        }
        *(bf16x4*)&Ah[r][c] = hv;
        *(bf16x4*)&Al[r][c] = lv;
    }
    __syncthreads();
    mfma_from_lds<SCALE>(Bh, Bl, C, rdeg, M, row0, tid, Ah, Al);
}

// ---------------- fused: ELL build (1 atomic + 1 store per edge) + layer-1 GEMMs (src-norm folded) ----------------
// blockIdx.x % 7 in {0,1} -> GEMM tile (BM=64); else -> 256 edges of build.
// ELL entries are uint16 (node ids < 65536): halves scattered write-allocate footprint.
__global__ __launch_bounds__(256) void fused_build_gemm(
    const int* __restrict__ s0, const int* __restrict__ d0, int* c0, unsigned short* e0, int E0, int B0,
    const int* __restrict__ s1, const int* __restrict__ d1, int* c1, unsigned short* e1, int E1, int B1,
    const int* __restrict__ s2, const int* __restrict__ d2, int* c2, unsigned short* e2, int E2,
    const float* __restrict__ xc, const float* __restrict__ xg,
    const __bf16* __restrict__ wt_h, const __bf16* __restrict__ wt_l,
    const int* __restrict__ degs_cg, const int* __restrict__ degs_cc, const int* __restrict__ degs_gc,
    _Float16* __restrict__ t_cg, _Float16* __restrict__ t_cc, _Float16* __restrict__ t_gc,
    int Nc, int Ng, int gBc, int G, int EB)
{
    __shared__ __bf16 Ah[64][136];
    __shared__ __bf16 Al[64][136];
    const int idx = blockIdx.x;
    const int r7 = idx % 7, q = idx / 7;
    if (r7 < 2) {
        int g = q * 2 + r7;
        if (g >= G) return;
        if (g < gBc)
            gemm_core<0, 1>(xc, wt_h, wt_l, t_cg, degs_cg, Nc, g * 64, threadIdx.x, Ah, Al);
        else if (g < 2 * gBc)
            gemm_core<0, 1>(xc, wt_h + 16384, wt_l + 16384, t_cc, degs_cc, Nc, (g - gBc) * 64, threadIdx.x, Ah, Al);
        else
            gemm_core<0, 1>(xg, wt_h + 2 * 16384, wt_l + 2 * 16384, t_gc, degs_gc, Ng, (g - 2 * gBc) * 64, threadIdx.x, Ah, Al);
    } else {
        int eb = q * 5 + (r7 - 2);
        if (eb >= EB) return;
        const int* src; const int* dst; int* cnt; unsigned short* ell; int E; int base;
        if (eb < B0)            { src = s0; dst = d0; cnt = c0; ell = e0; E = E0; base = eb; }
        else if (eb < B0 + B1)  { src = s1; dst = d1; cnt = c1; ell = e1; E = E1; base = eb - B0; }
        else                    { src = s2; dst = d2; cnt = c2; ell = e2; E = E2; base = eb - B0 - B1; }
        int i = base * 256 + threadIdx.x;
        if (i < E) {
            int s = src[i];
            int d = dst[i];
            int p = atomicAdd(&cnt[d], 1);
            if (p < ELLW) ell[d * ELLW + p] = (unsigned short)s;
        }
    }
}

// ---------------- gather helper: one row per 16-lane group, 4-deep load burst ----------------
// each lane reads its h8 (16B) slice of the 256B row; pure accumulate (rows pre-scaled by src-norm).
__device__ __forceinline__ void rel_accum_g(const _Float16* __restrict__ feat,
    const unsigned short* __restrict__ cp, int n, int c8, float* acc)
{
    int i = 0;
    for (; i + 3 < n; i += 4) {
        int q0 = cp[i], q1 = cp[i + 1], q2 = cp[i + 2], q3 = cp[i + 3];
        h8 v0 = *(const h8*)(feat + (size_t)q0 * 128 + c8);
        h8 v1 = *(const h8*)(feat + (size_t)q1 * 128 + c8);
        h8 v2 = *(const h8*)(feat + (size_t)q2 * 128 + c8);
        h8 v3 = *(const h8*)(feat + (size_t)q3 * 128 + c8);
#pragma unroll
        for (int j = 0; j < 8; ++j)
            acc[j] += ((float)v0[j] + (float)v1[j]) + ((float)v2[j] + (float)v3[j]);
    }
    for (; i < n; ++i) {
        int q0 = cp[i];
        h8 v0 = *(const h8*)(feat + (size_t)q0 * 128 + c8);
#pragma unroll
        for (int j = 0; j < 8; ++j) acc[j] += (float)v0[j];
    }
}

// ---------------- fused layer-1 gather + layer-2 GEMM ----------------
// One 64-row output tile per block. Phase 1: each 16-lane group gathers 4 h1 rows
// (dual cc+gc for chem blocks, cg for gene blocks), applies dst-norm + bias + leaky-relu
// in f32, writes bf16 hi/lo split into the LDS A-tile. Phase 2: MFMA with W2,
// sharded src-norm folded into the epilogue. Eliminates the h1 round-trip entirely.
__global__ __launch_bounds__(256) void gather_gemm2(
    const _Float16* __restrict__ t_cg, const unsigned short* __restrict__ ell_cg,
    const int* __restrict__ cnt_cg,
    const _Float16* __restrict__ f_cc, const unsigned short* __restrict__ ell_cc,
    const int* __restrict__ cnt_cc,
    const _Float16* __restrict__ t_gc, const unsigned short* __restrict__ ell_gc,
    const int* __restrict__ cnt_gc,
    const float* __restrict__ b1_cg, const float* __restrict__ b1_cc, const float* __restrict__ b1_gc,
    const __bf16* __restrict__ wt_h, const __bf16* __restrict__ wt_l,
    const int* __restrict__ degs_cc, const int* __restrict__ degs_gc,
    _Float16* __restrict__ t2_cc, _Float16* __restrict__ t2_gc,
    int Nc, int Ng, int gBc)
{
    __shared__ __bf16 Ah[64][136];
    __shared__ __bf16 Al[64][136];
    const int grp = threadIdx.x >> 4;        // 0..15
    const int c8 = (threadIdx.x & 15) << 3;  // column offset (8 elems)
    const bool chem = (int)blockIdx.x < gBc;
    const int row0 = chem ? (int)blockIdx.x * 64 : ((int)blockIdx.x - gBc) * 64;
    const int M = chem ? Nc : Ng;

    // ---- phase 1: gather 4 rows per group into the LDS A-tile ----
    for (int rr = 0; rr < 4; ++rr) {
        int rl = grp * 4 + rr;      // local row 0..63
        int row = row0 + rl;
        float r[8] = {};
        if (row < M) {
            if (chem) {
                int na = cnt_cc[row];
                float wa = rsqrtf(fmaxf((float)na, 1.0f));
                if (na > ELLW) na = ELLW;
                float accA[8] = {};
                rel_accum_g(f_cc, ell_cc + row * ELLW, na, c8, accA);
                int nb = cnt_gc[row];
                float wb = rsqrtf(fmaxf((float)nb, 1.0f));
                if (nb > ELLW) nb = ELLW;
                float accB[8] = {};
                rel_accum_g(t_gc, ell_gc + row * ELLW, nb, c8, accB);
                f4 b0lo = *(const f4*)(b1_cc + c8);
                f4 b0hi = *(const f4*)(b1_cc + c8 + 4);
                f4 b1lo = *(const f4*)(b1_gc + c8);
                f4 b1hi = *(const f4*)(b1_gc + c8 + 4);
#pragma unroll
                for (int j = 0; j < 4; ++j) r[j] = accA[j] * wa + accB[j] * wb + b0lo[j] + b1lo[j];
#pragma unroll
                for (int j = 0; j < 4; ++j) r[4 + j] = accA[4 + j] * wa + accB[4 + j] * wb + b0hi[j] + b1hi[j];
            } else {
                int n = cnt_cg[row];
                float wd = rsqrtf(fmaxf((float)n, 1.0f));
                if (n > ELLW) n = ELLW;
                float acc[8] = {};
                rel_accum_g(t_cg, ell_cg + row * ELLW, n, c8, acc);
                f4 blo = *(const f4*)(b1_cg + c8);
                f4 bhi = *(const f4*)(b1_cg + c8 + 4);
#pragma unroll
                for (int j = 0; j < 4; ++j) r[j] = acc[j] * wd + blo[j];
#pragma unroll
                for (int j = 0; j < 4; ++j) r[4 + j] = acc[4 + j] * wd + bhi[j];
            }
        }
        bf16x8 hv, lv;
#pragma unroll
        for (int j = 0; j < 8; ++j) {
            float v = r[j];
            v = v >= 0.f ? v : v * NEG_SLOPE;   // leaky relu in f32 (h1 activation)
            __bf16 h = (__bf16)v;
            hv[j] = h;
            lv[j] = (__bf16)(v - (float)h);
        }
        *(bf16x8*)&Ah[rl][c8] = hv;
        *(bf16x8*)&Al[rl][c8] = lv;
    }
    __syncthreads();

    // ---- phase 2: MFMA with W2, sharded src-norm epilogue ----
    if (chem)
        mfma_from_lds<1>(wt_h + 3 * 16384, wt_l + 3 * 16384, t2_cc, degs_cc, Nc, row0, threadIdx.x, Ah, Al);
    else
        mfma_from_lds<1>(wt_h + 4 * 16384, wt_l + 4 * 16384, t2_gc, degs_gc, Ng, row0, threadIdx.x, Ah, Al);
}

// ---------------- final dual gather -> d_out (f32), 16 rows per block ----------------
__global__ __launch_bounds__(256) void gather_l2(
    const _Float16* __restrict__ fA, const unsigned short* __restrict__ ellA,
    const int* __restrict__ cntA,
    const _Float16* __restrict__ fB, const unsigned short* __restrict__ ellB,
    const int* __restrict__ cntB,
    const float* __restrict__ bA, const float* __restrict__ bB,
    float* __restrict__ out, int Nd)
{
    const int grp = threadIdx.x >> 4;
    const int c8 = (threadIdx.x & 15) << 3;
    int row = blockIdx.x * 16 + grp;
    if (row >= Nd) return;
    int na = cntA[row];
    float wa = rsqrtf(fmaxf((float)na, 1.0f));
    if (na > ELLW) na = ELLW;
    float accA[8] = {};
    rel_accum_g(fA, ellA + row * ELLW, na, c8, accA);
    int nb = cntB[row];
    float wb = rsqrtf(fmaxf((float)nb, 1.0f));
    if (nb > ELLW) nb = ELLW;
    float accB[8] = {};
    rel_accum_g(fB, ellB + row * ELLW, nb, c8, accB);
    f4 balo = *(const f4*)(bA + c8);
    f4 bahi = *(const f4*)(bA + c8 + 4);
    f4 bblo = *(const f4*)(bB + c8);
    f4 bbhi = *(const f4*)(bB + c8 + 4);
    f4 olo, ohi;
#pragma unroll
    for (int j = 0; j < 4; ++j) olo[j] = accA[j] * wa + accB[j] * wb + balo[j] + bblo[j];
#pragma unroll
    for (int j = 0; j < 4; ++j) ohi[j] = accA[4 + j] * wa + accB[4 + j] * wb + bahi[j] + bbhi[j];
    *(f4*)(out + (size_t)row * 128 + c8) = olo;
    *(f4*)(out + (size_t)row * 128 + c8 + 4) = ohi;
}

extern "C" void kernel_launch(void* const* d_in, const int* in_sizes, int n_in,
                              void* d_out, int out_size, void* d_ws, size_t ws_size,
                              hipStream_t stream)
{
    const float* x_chem = (const float*)d_in[0];
    const float* x_gene = (const float*)d_in[1];
    const int* src_cc = (const int*)d_in[2];
    const int* dst_cc = (const int*)d_in[3];
    const int* src_cg = (const int*)d_in[4];
    const int* dst_cg = (const int*)d_in[5];
    const int* src_gc = (const int*)d_in[6];
    const int* dst_gc = (const int*)d_in[7];
    const float* W1_cc = (const float*)d_in[8];
    const float* W1_cg = (const float*)d_in[9];
    const float* W1_gc = (const float*)d_in[10];
    const float* W2_cc = (const float*)d_in[11];
    const float* W2_gc = (const float*)d_in[13];
    const float* b1_cc = (const float*)d_in[14];
    const float* b1_cg = (const float*)d_in[15];
    const float* b1_gc = (const float*)d_in[16];
    const float* b2_cc = (const float*)d_in[17];
    const float* b2_gc = (const float*)d_in[19];
    (void)n_in; (void)out_size; (void)ws_size;

    const int Nc = in_sizes[0] / 128;
    const int Ng = in_sizes[1] / 128;
    const int Ecc = in_sizes[2];
    const int Ecg = in_sizes[4];
    const int Egc = in_sizes[6];

    // ---------------- workspace layout ----------------
    int* cnt_cc  = (int*)d_ws;           // in-deg cc (zeroed region start)
    int* cnt_cg  = cnt_cc + Nc;          // in-deg cg (Ng)
    int* cnt_gc  = cnt_cg + Ng;          // in-deg gc (Nc)
    int* degs_cc = cnt_gc + Nc;          // out-deg chem (cc), NSH shards of Nc
    int* degs_cg = degs_cc + NSH * Nc;   // out-deg chem (cg), NSH shards of Nc
    int* degs_gc = degs_cg + NSH * Nc;   // out-deg gene (gc), NSH shards of Ng
    const int degTotal = (2 * Nc + Ng) + NSH * (2 * Nc + Ng);
    unsigned short* ell_cc = (unsigned short*)(degs_gc + NSH * Ng);
    unsigned short* ell_cg = ell_cc + (size_t)Nc * ELLW;
    unsigned short* ell_gc = ell_cg + (size_t)Ng * ELLW;
    size_t off = (size_t)((char*)(ell_gc + (size_t)Nc * ELLW) - (char*)d_ws);
    off = (off + 255) & ~(size_t)255;
    _Float16* t2_cc   = (_Float16*)((char*)d_ws + off);  // layer2 cc table (Nc*128)
    _Float16* t2_gc   = t2_cc + (size_t)Nc * 128;        // layer2 gc table (Ng*128)
    _Float16* tmp_cg  = t2_gc + (size_t)Ng * 128;        // layer1 cg table (Nc*128)
    _Float16* tmp_gc  = tmp_cg + (size_t)Nc * 128;       // layer1 gc table (Ng*128)
    _Float16* tmp_cc  = tmp_gc + (size_t)Ng * 128;       // layer1 cc table (Nc*128)
    __bf16* wt_h = (__bf16*)(tmp_cc + (size_t)Nc * 128); // 5 * 16384 bf16
    __bf16* wt_l = wt_h + 5 * 16384;
    float* outF = (float*)d_out;

    dim3 blk(256);
    const int B0 = (Ecc + 255) / 256, B1 = (Ecg + 255) / 256, B2 = (Egc + 255) / 256;
    const int EB = B0 + B1 + B2;
    const int gBc = (Nc + 63) / 64, gBg = (Ng + 63) / 64;
    const int G = 2 * gBc + gBg;
    int Q = (G + 1) / 2;
    if ((EB + 4) / 5 > Q) Q = (EB + 4) / 5;
    const int T = 7 * Q;

    // zero degree/counter region (graph-capture-safe async memset)
    hipMemsetAsync(d_ws, 0, (size_t)degTotal * sizeof(int), stream);

    // W prep + sharded out-degree count in one kernel
    const int Etot = Ecc + Ecg + Egc;
    const int CB = (Etot + 1023) / 1024;
    prep_w_count<<<320 + CB, blk, 0, stream>>>(W1_cg, W1_cc, W1_gc, W2_cc, W2_gc,
        wt_h, wt_l,
        src_cc, degs_cc, Ecc, Nc,
        src_cg, degs_cg, Ecg, Nc,
        src_gc, degs_gc, Egc, Ng, CB);

    // fused: ELL build + all three layer-1 GEMMs (sharded src-norm folded, f16 outputs)
    fused_build_gemm<<<T, blk, 0, stream>>>(
        src_cc, dst_cc, cnt_cc, ell_cc, Ecc, B0,
        src_cg, dst_cg, cnt_cg, ell_cg, Ecg, B1,
        src_gc, dst_gc, cnt_gc, ell_gc, Egc,
        x_chem, x_gene, wt_h, wt_l,
        degs_cg, degs_cc, degs_gc,
        tmp_cg, tmp_cc, tmp_gc,
        Nc, Ng, gBc, G, EB);

    // ---- fused layer-1 gather + layer-2 GEMM (no h1 round-trip) ----
    gather_gemm2<<<gBc + gBg, blk, 0, stream>>>(
        tmp_cg, ell_cg, cnt_cg,
        tmp_cc, ell_cc, cnt_cc,
        tmp_gc, ell_gc, cnt_gc,
        b1_cg, b1_cc, b1_gc,
        wt_h, wt_l, degs_cc, degs_gc,
        t2_cc, t2_gc, Nc, Ng, gBc);

    // ---- final dual gather -> out (f32) ----
    const int Bc = (Nc + 15) / 16;
    gather_l2<<<Bc, blk, 0, stream>>>(
        t2_cc, ell_cc, cnt_cc,
        t2_gc, ell_gc, cnt_gc,
        b2_cc, b2_gc, outF, Nc);
}

// Round 9
// 366.833 us; speedup vs baseline: 1.0266x; 1.0266x over previous
//
#include <hip/hip_runtime.h>
#include <math.h>

#define NEG_SLOPE 0.01f
#define ELLW 40   // max in-degree per relation (Poisson(10); P(overflow)~1e-8, clamped)

typedef float f4 __attribute__((ext_vector_type(4)));
typedef __bf16 bf16x8 __attribute__((ext_vector_type(8)));
typedef __bf16 bf16x4 __attribute__((ext_vector_type(4)));
typedef _Float16 h4 __attribute__((ext_vector_type(4)));
typedef _Float16 h8 __attribute__((ext_vector_type(8)));

// ---------------- W prep (transpose + bf16 split, 5 weights) + out-degree count ----------------
// degree region is zeroed by hipMemsetAsync before this kernel.
// blocks [0,320): W prep ; blocks [320,320+CB): grid-strided out-degree atomics (fire-and-forget).
__global__ __launch_bounds__(256) void prep_w_count(
    const float* __restrict__ W0, const float* __restrict__ W1,
    const float* __restrict__ W2, const float* __restrict__ W3,
    const float* __restrict__ W4, __bf16* __restrict__ H, __bf16* __restrict__ L,
    const int* __restrict__ s0, int* sd0, int E0,
    const int* __restrict__ s1, int* sd1, int E1,
    const int* __restrict__ s2, int* sd2, int E2, int CB)
{
    const int b = blockIdx.x;
    if (b < 320) {
        const int y = b >> 6;
        const float* W = y == 0 ? W0 : y == 1 ? W1 : y == 2 ? W2 : y == 3 ? W3 : W4;
        int idx = (b & 63) * 256 + threadIdx.x;   // 0..16383
        int k = idx >> 7, n = idx & 127;
        float w = W[idx];
        __bf16 h = (__bf16)w;
        __bf16 l = (__bf16)(w - (float)h);
        H[(size_t)y * 16384 + n * 128 + k] = h;
        L[(size_t)y * 16384 + n * 128 + k] = l;
    } else {
        int cb = b - 320;
        int stride = CB * 256;
        int Etot = E0 + E1 + E2;
        for (int i = cb * 256 + (int)threadIdx.x; i < Etot; i += stride) {
            int s; int* sd;
            if (i < E0)           { s = s0[i]; sd = sd0; }
            else if (i < E0 + E1) { s = s1[i - E0]; sd = sd1; }
            else                  { s = s2[i - E0 - E1]; sd = sd2; }
            atomicAdd(&sd[s], 1);
        }
    }
}

// ---------------- MFMA GEMM core (bf16 3-split): C[64 rows,128] = f(A) @ W ----------------
// A may be f32 (layer 1, raw inputs) or f16 (layer 2, intermediate tables). C is always f16.
// SCALE: multiply each output row by rsqrt(max(rdeg[row],1)) (src-norm folding).
template <int RELU, int SCALE, typename T>
__device__ __forceinline__ void gemm_core(const T* __restrict__ A,
    const __bf16* __restrict__ Bh, const __bf16* __restrict__ Bl,
    _Float16* __restrict__ C, const int* __restrict__ rdeg, int M, int row0, int tid,
    __bf16 (*Ah)[136], __bf16 (*Al)[136])
{
    if constexpr (sizeof(T) == 4) {
#pragma unroll
        for (int it = 0; it < 8; ++it) {
            int idx4 = it * 256 + tid;
            int r = idx4 >> 5;
            int c = (idx4 & 31) << 2;
            int rg = row0 + r;
            f4 v = {0.f, 0.f, 0.f, 0.f};
            if (rg < M) v = *(const f4*)(A + (size_t)rg * 128 + c);
            if (RELU) {
#pragma unroll
                for (int j = 0; j < 4; ++j) v[j] = v[j] >= 0.f ? v[j] : v[j] * NEG_SLOPE;
            }
            bf16x4 hv, lv;
#pragma unroll
            for (int j = 0; j < 4; ++j) {
                __bf16 h = (__bf16)v[j];
                hv[j] = h;
                lv[j] = (__bf16)(v[j] - (float)h);
            }
            *(bf16x4*)&Ah[r][c] = hv;
            *(bf16x4*)&Al[r][c] = lv;
        }
    } else {
#pragma unroll
        for (int it = 0; it < 4; ++it) {
            int idx8 = it * 256 + tid;
            int r = idx8 >> 4;
            int c = (idx8 & 15) << 3;
            int rg = row0 + r;
            h8 v8 = {};
            if (rg < M) v8 = *(const h8*)(A + (size_t)rg * 128 + c);
            bf16x8 hv, lv;
#pragma unroll
            for (int j = 0; j < 8; ++j) {
                float v = (float)v8[j];
                if (RELU) v = v >= 0.f ? v : v * NEG_SLOPE;
                __bf16 h = (__bf16)v;
                hv[j] = h;
                lv[j] = (__bf16)(v - (float)h);
            }
            *(bf16x8*)&Ah[r][c] = hv;
            *(bf16x8*)&Al[r][c] = lv;
        }
    }
    __syncthreads();

    const int lane = tid & 63;
    const int wid = tid >> 6;
    const int lm = lane & 15;
    const int lq = lane >> 4;
    const int mbase = (wid & 1) * 32;
    const int nbase = (wid >> 1) * 64;

    f4 acc[2][4] = {};
#pragma unroll
    for (int kc = 0; kc < 4; ++kc) {
        const int koff = kc * 32 + lq * 8;
        bf16x8 ah[2], al[2], bh[4], bl[4];
#pragma unroll
        for (int mi = 0; mi < 2; ++mi) {
            ah[mi] = *(const bf16x8*)&Ah[mbase + mi * 16 + lm][koff];
            al[mi] = *(const bf16x8*)&Al[mbase + mi * 16 + lm][koff];
        }
#pragma unroll
        for (int ni = 0; ni < 4; ++ni) {
            size_t boff = (size_t)(nbase + ni * 16 + lm) * 128 + koff;
            bh[ni] = *(const bf16x8*)(Bh + boff);
            bl[ni] = *(const bf16x8*)(Bl + boff);
        }
#pragma unroll
        for (int mi = 0; mi < 2; ++mi)
#pragma unroll
            for (int ni = 0; ni < 4; ++ni) {
                acc[mi][ni] = __builtin_amdgcn_mfma_f32_16x16x32_bf16(ah[mi], bh[ni], acc[mi][ni], 0, 0, 0);
                acc[mi][ni] = __builtin_amdgcn_mfma_f32_16x16x32_bf16(al[mi], bh[ni], acc[mi][ni], 0, 0, 0);
                acc[mi][ni] = __builtin_amdgcn_mfma_f32_16x16x32_bf16(ah[mi], bl[ni], acc[mi][ni], 0, 0, 0);
            }
    }

#pragma unroll
    for (int mi = 0; mi < 2; ++mi) {
        int rbase = row0 + mbase + mi * 16 + lq * 4;
#pragma unroll
        for (int r = 0; r < 4; ++r) {
            int row = rbase + r;
            if (row < M) {
                float s = 1.0f;
                if (SCALE) s = rsqrtf(fmaxf((float)rdeg[row], 1.0f));
#pragma unroll
                for (int ni = 0; ni < 4; ++ni)
                    C[(size_t)row * 128 + nbase + ni * 16 + lm] = (_Float16)(acc[mi][ni][r] * s);
            }
        }
    }
}

// ---------------- fused: ELL build (1 atomic + 1 store per edge) + layer-1 GEMMs (src-norm folded) ----------------
// blockIdx.x % 7 in {0,1} -> GEMM tile (BM=64); else -> 256 edges of build.
// ELL entries are uint16 (node ids < 65536): halves scattered write-allocate footprint.
__global__ __launch_bounds__(256) void fused_build_gemm(
    const int* __restrict__ s0, const int* __restrict__ d0, int* c0, unsigned short* e0, int E0, int B0,
    const int* __restrict__ s1, const int* __restrict__ d1, int* c1, unsigned short* e1, int E1, int B1,
    const int* __restrict__ s2, const int* __restrict__ d2, int* c2, unsigned short* e2, int E2,
    const float* __restrict__ xc, const float* __restrict__ xg,
    const __bf16* __restrict__ wt_h, const __bf16* __restrict__ wt_l,
    const int* __restrict__ degs_cg, const int* __restrict__ degs_cc, const int* __restrict__ degs_gc,
    _Float16* __restrict__ t_cg, _Float16* __restrict__ t_cc, _Float16* __restrict__ t_gc,
    int Nc, int Ng, int gBc, int G, int EB)
{
    __shared__ __bf16 Ah[64][136];
    __shared__ __bf16 Al[64][136];
    const int idx = blockIdx.x;
    const int r7 = idx % 7, q = idx / 7;
    if (r7 < 2) {
        int g = q * 2 + r7;
        if (g >= G) return;
        if (g < gBc)
            gemm_core<0, 1>(xc, wt_h, wt_l, t_cg, degs_cg, Nc, g * 64, threadIdx.x, Ah, Al);
        else if (g < 2 * gBc)
            gemm_core<0, 1>(xc, wt_h + 16384, wt_l + 16384, t_cc, degs_cc, Nc, (g - gBc) * 64, threadIdx.x, Ah, Al);
        else
            gemm_core<0, 1>(xg, wt_h + 2 * 16384, wt_l + 2 * 16384, t_gc, degs_gc, Ng, (g - 2 * gBc) * 64, threadIdx.x, Ah, Al);
    } else {
        int eb = q * 5 + (r7 - 2);
        if (eb >= EB) return;
        const int* src; const int* dst; int* cnt; unsigned short* ell; int E; int base;
        if (eb < B0)            { src = s0; dst = d0; cnt = c0; ell = e0; E = E0; base = eb; }
        else if (eb < B0 + B1)  { src = s1; dst = d1; cnt = c1; ell = e1; E = E1; base = eb - B0; }
        else                    { src = s2; dst = d2; cnt = c2; ell = e2; E = E2; base = eb - B0 - B1; }
        int i = base * 256 + threadIdx.x;
        if (i < E) {
            int s = src[i];
            int d = dst[i];
            int p = atomicAdd(&cnt[d], 1);
            if (p < ELLW) ell[d * ELLW + p] = (unsigned short)s;
        }
    }
}

// ---------------- combined layer-2 GEMM (relu + src-norm fused), f16 in / f16 out ----------------
__global__ __launch_bounds__(256) void gemm2_both(
    const _Float16* __restrict__ h1c, const _Float16* __restrict__ h1g,
    const __bf16* __restrict__ wt_h, const __bf16* __restrict__ wt_l,
    const int* __restrict__ degs_cc, const int* __restrict__ degs_gc,
    _Float16* __restrict__ t_cc, _Float16* __restrict__ t_gc, int Nc, int Ng, int gBc)
{
    __shared__ __bf16 Ah[64][136];
    __shared__ __bf16 Al[64][136];
    if ((int)blockIdx.x < gBc)
        gemm_core<1, 1>(h1c, wt_h + 3 * 16384, wt_l + 3 * 16384, t_cc, degs_cc, Nc, blockIdx.x * 64, threadIdx.x, Ah, Al);
    else
        gemm_core<1, 1>(h1g, wt_h + 4 * 16384, wt_l + 4 * 16384, t_gc, degs_gc, Ng, (blockIdx.x - gBc) * 64, threadIdx.x, Ah, Al);
}

// ---------------- gather helper: one row per 16-lane group, 4-deep load burst ----------------
// each lane reads its h8 (16B) slice of the 256B row; pure accumulate (rows pre-scaled by src-norm).
__device__ __forceinline__ void rel_accum_g(const _Float16* __restrict__ feat,
    const unsigned short* __restrict__ cp, int n, int c8, float* acc)
{
    int i = 0;
    for (; i + 3 < n; i += 4) {
        int q0 = cp[i], q1 = cp[i + 1], q2 = cp[i + 2], q3 = cp[i + 3];
        h8 v0 = *(const h8*)(feat + (size_t)q0 * 128 + c8);
        h8 v1 = *(const h8*)(feat + (size_t)q1 * 128 + c8);
        h8 v2 = *(const h8*)(feat + (size_t)q2 * 128 + c8);
        h8 v3 = *(const h8*)(feat + (size_t)q3 * 128 + c8);
#pragma unroll
        for (int j = 0; j < 8; ++j)
            acc[j] += ((float)v0[j] + (float)v1[j]) + ((float)v2[j] + (float)v3[j]);
    }
    for (; i < n; ++i) {
        int q0 = cp[i];
        h8 v0 = *(const h8*)(feat + (size_t)q0 * 128 + c8);
#pragma unroll
        for (int j = 0; j < 8; ++j) acc[j] += (float)v0[j];
    }
}

// ---------------- combined layer-1 gathers: blocks < Bg do cg->h1_gene; rest dual cc+gc->h1_chem ----------------
// 16 rows per block (one row per 16-lane group); no cross-lane reduction needed.
__global__ __launch_bounds__(256) void gather_l1(
    const _Float16* __restrict__ t_cg, const unsigned short* __restrict__ ell_cg,
    const int* __restrict__ cnt_cg,
    const _Float16* __restrict__ f_cc, const unsigned short* __restrict__ ell_cc,
    const int* __restrict__ cnt_cc,
    const _Float16* __restrict__ t_gc, const unsigned short* __restrict__ ell_gc,
    const int* __restrict__ cnt_gc,
    const float* __restrict__ b1_cg, const float* __restrict__ b1_cc, const float* __restrict__ b1_gc,
    _Float16* __restrict__ h1_gene, _Float16* __restrict__ h1_chem, int Ng, int Nc, int Bg)
{
    const int grp = threadIdx.x >> 4;
    const int c8 = (threadIdx.x & 15) << 3;
    if ((int)blockIdx.x < Bg) {
        int row = blockIdx.x * 16 + grp;
        if (row >= Ng) return;
        int n = cnt_cg[row];
        float wd = rsqrtf(fmaxf((float)n, 1.0f));
        if (n > ELLW) n = ELLW;
        float acc[8] = {};
        rel_accum_g(t_cg, ell_cg + row * ELLW, n, c8, acc);
        f4 blo = *(const f4*)(b1_cg + c8);
        f4 bhi = *(const f4*)(b1_cg + c8 + 4);
        h8 o;
#pragma unroll
        for (int j = 0; j < 4; ++j) o[j] = (_Float16)(acc[j] * wd + blo[j]);
#pragma unroll
        for (int j = 0; j < 4; ++j) o[4 + j] = (_Float16)(acc[4 + j] * wd + bhi[j]);
        *(h8*)(h1_gene + (size_t)row * 128 + c8) = o;
    } else {
        int row = (blockIdx.x - Bg) * 16 + grp;
        if (row >= Nc) return;
        int na = cnt_cc[row];
        float wa = rsqrtf(fmaxf((float)na, 1.0f));
        if (na > ELLW) na = ELLW;
        float accA[8] = {};
        rel_accum_g(f_cc, ell_cc + row * ELLW, na, c8, accA);
        int nb = cnt_gc[row];
        float wb = rsqrtf(fmaxf((float)nb, 1.0f));
        if (nb > ELLW) nb = ELLW;
        float accB[8] = {};
        rel_accum_g(t_gc, ell_gc + row * ELLW, nb, c8, accB);
        f4 b0lo = *(const f4*)(b1_cc + c8);
        f4 b0hi = *(const f4*)(b1_cc + c8 + 4);
        f4 b1lo = *(const f4*)(b1_gc + c8);
        f4 b1hi = *(const f4*)(b1_gc + c8 + 4);
        h8 o;
#pragma unroll
        for (int j = 0; j < 4; ++j) o[j] = (_Float16)(accA[j] * wa + accB[j] * wb + b0lo[j] + b1lo[j]);
#pragma unroll
        for (int j = 0; j < 4; ++j) o[4 + j] = (_Float16)(accA[4 + j] * wa + accB[4 + j] * wb + b0hi[j] + b1hi[j]);
        *(h8*)(h1_chem + (size_t)row * 128 + c8) = o;
    }
}

// ---------------- final dual gather -> d_out (f32), 16 rows per block ----------------
__global__ __launch_bounds__(256) void gather_l2(
    const _Float16* __restrict__ fA, const unsigned short* __restrict__ ellA,
    const int* __restrict__ cntA,
    const _Float16* __restrict__ fB, const unsigned short* __restrict__ ellB,
    const int* __restrict__ cntB,
    const float* __restrict__ bA, const float* __restrict__ bB,
    float* __restrict__ out, int Nd)
{
    const int grp = threadIdx.x >> 4;
    const int c8 = (threadIdx.x & 15) << 3;
    int row = blockIdx.x * 16 + grp;
    if (row >= Nd) return;
    int na = cntA[row];
    float wa = rsqrtf(fmaxf((float)na, 1.0f));
    if (na > ELLW) na = ELLW;
    float accA[8] = {};
    rel_accum_g(fA, ellA + row * ELLW, na, c8, accA);
    int nb = cntB[row];
    float wb = rsqrtf(fmaxf((float)nb, 1.0f));
    if (nb > ELLW) nb = ELLW;
    float accB[8] = {};
    rel_accum_g(fB, ellB + row * ELLW, nb, c8, accB);
    f4 balo = *(const f4*)(bA + c8);
    f4 bahi = *(const f4*)(bA + c8 + 4);
    f4 bblo = *(const f4*)(bB + c8);
    f4 bbhi = *(const f4*)(bB + c8 + 4);
    f4 olo, ohi;
#pragma unroll
    for (int j = 0; j < 4; ++j) olo[j] = accA[j] * wa + accB[j] * wb + balo[j] + bblo[j];
#pragma unroll
    for (int j = 0; j < 4; ++j) ohi[j] = accA[4 + j] * wa + accB[4 + j] * wb + bahi[j] + bbhi[j];
    *(f4*)(out + (size_t)row * 128 + c8) = olo;
    *(f4*)(out + (size_t)row * 128 + c8 + 4) = ohi;
}

extern "C" void kernel_launch(void* const* d_in, const int* in_sizes, int n_in,
                              void* d_out, int out_size, void* d_ws, size_t ws_size,
                              hipStream_t stream)
{
    const float* x_chem = (const float*)d_in[0];
    const float* x_gene = (const float*)d_in[1];
    const int* src_cc = (const int*)d_in[2];
    const int* dst_cc = (const int*)d_in[3];
    const int* src_cg = (const int*)d_in[4];
    const int* dst_cg = (const int*)d_in[5];
    const int* src_gc = (const int*)d_in[6];
    const int* dst_gc = (const int*)d_in[7];
    const float* W1_cc = (const float*)d_in[8];
    const float* W1_cg = (const float*)d_in[9];
    const float* W1_gc = (const float*)d_in[10];
    const float* W2_cc = (const float*)d_in[11];
    const float* W2_gc = (const float*)d_in[13];
    const float* b1_cc = (const float*)d_in[14];
    const float* b1_cg = (const float*)d_in[15];
    const float* b1_gc = (const float*)d_in[16];
    const float* b2_cc = (const float*)d_in[17];
    const float* b2_gc = (const float*)d_in[19];
    (void)n_in; (void)out_size; (void)ws_size;

    const int Nc = in_sizes[0] / 128;
    const int Ng = in_sizes[1] / 128;
    const int Ecc = in_sizes[2];
    const int Ecg = in_sizes[4];
    const int Egc = in_sizes[6];

    // ---------------- workspace layout ----------------
    int* cnt_cc  = (int*)d_ws;           // in-deg cc (zeroed region start)
    int* cnt_cg  = cnt_cc + Nc;          // in-deg cg (Ng)
    int* cnt_gc  = cnt_cg + Ng;          // in-deg gc (Nc)
    int* degs_cc = cnt_gc + Nc;          // out-deg chem (cc)
    int* degs_cg = degs_cc + Nc;         // out-deg chem (cg)
    int* degs_gc = degs_cg + Nc;         // out-deg gene (gc) (Ng)
    const int degTotal = 4 * Nc + 2 * Ng;
    unsigned short* ell_cc = (unsigned short*)(degs_gc + Ng);
    unsigned short* ell_cg = ell_cc + (size_t)Nc * ELLW;
    unsigned short* ell_gc = ell_cg + (size_t)Ng * ELLW;
    size_t off = (size_t)((char*)(ell_gc + (size_t)Nc * ELLW) - (char*)d_ws);
    off = (off + 255) & ~(size_t)255;
    _Float16* h1_chem = (_Float16*)((char*)d_ws + off);  // Nc*128
    _Float16* h1_gene = h1_chem + (size_t)Nc * 128;      // Ng*128
    _Float16* tmp_cg  = h1_gene + (size_t)Ng * 128;      // layer1 cg out; reused as layer2 cc out (Nc*128)
    _Float16* tmp_gc  = tmp_cg + (size_t)Nc * 128;       // layer1 gc out; reused as layer2 gc out (Ng*128)
    _Float16* tmp_cc  = tmp_gc + (size_t)Ng * 128;       // layer1 cc out (Nc*128)
    __bf16* wt_h = (__bf16*)(tmp_cc + (size_t)Nc * 128); // 5 * 16384 bf16
    __bf16* wt_l = wt_h + 5 * 16384;
    float* outF = (float*)d_out;

    dim3 blk(256);
    const int B0 = (Ecc + 255) / 256, B1 = (Ecg + 255) / 256, B2 = (Egc + 255) / 256;
    const int EB = B0 + B1 + B2;
    const int gBc = (Nc + 63) / 64, gBg = (Ng + 63) / 64;
    const int G = 2 * gBc + gBg;
    int Q = (G + 1) / 2;
    if ((EB + 4) / 5 > Q) Q = (EB + 4) / 5;
    const int T = 7 * Q;

    // zero degree/counter region (graph-capture-safe async memset)
    hipMemsetAsync(d_ws, 0, (size_t)degTotal * sizeof(int), stream);

    // W prep + out-degree count in one kernel (count grid-strided, ~4 edges/thread)
    const int Etot = Ecc + Ecg + Egc;
    const int CB = (Etot + 1023) / 1024;
    prep_w_count<<<320 + CB, blk, 0, stream>>>(W1_cg, W1_cc, W1_gc, W2_cc, W2_gc,
        wt_h, wt_l,
        src_cc, degs_cc, Ecc,
        src_cg, degs_cg, Ecg,
        src_gc, degs_gc, Egc, CB);

    // fused: ELL build + all three layer-1 GEMMs (src-norm folded, f16 outputs)
    fused_build_gemm<<<T, blk, 0, stream>>>(
        src_cc, dst_cc, cnt_cc, ell_cc, Ecc, B0,
        src_cg, dst_cg, cnt_cg, ell_cg, Ecg, B1,
        src_gc, dst_gc, cnt_gc, ell_gc, Egc,
        x_chem, x_gene, wt_h, wt_l,
        degs_cg, degs_cc, degs_gc,
        tmp_cg, tmp_cc, tmp_gc,
        Nc, Ng, gBc, G, EB);

    // ---- all layer-1 gathers in one launch (tables pre-scaled; only dst-norm inline) ----
    const int Bg = (Ng + 15) / 16, Bc = (Nc + 15) / 16;
    gather_l1<<<Bg + Bc, blk, 0, stream>>>(
        tmp_cg, ell_cg, cnt_cg,
        tmp_cc, ell_cc, cnt_cc,
        tmp_gc, ell_gc, cnt_gc,
        b1_cg, b1_cc, b1_gc, h1_gene, h1_chem, Ng, Nc, Bg);

    // ---- both layer-2 GEMMs in one launch (src-norm folded into epilogue) ----
    gemm2_both<<<gBc + gBg, blk, 0, stream>>>(h1_chem, h1_gene, wt_h, wt_l,
        degs_cc, degs_gc, tmp_cg, tmp_gc, Nc, Ng, gBc);

    // ---- final dual gather -> out (f32) ----
    gather_l2<<<Bc, blk, 0, stream>>>(
        tmp_cg, ell_cc, cnt_cc,
        tmp_gc, ell_gc, cnt_gc,
        b2_cc, b2_gc, outF, Nc);
}